// Round 8
// baseline (189.736 us; speedup 1.0000x reference)
//
#include <hip/hip_runtime.h>

#define HH 512
#define WW 512
#define NBATCH 16
#define NBINS 512   // 511 real shells + 1 overflow (never read downstream)
#define NCQ 128     // column quads (4 columns per col block)

#define PI_F 3.14159265358979323846f

// Swizzle for the per-wave FFT exchange region (512 float2): keeps all three
// access phases at the conflict-free b64 baseline (verified, absmax 0).
#define SW(r) ((r) ^ (((r) >> 4) & 0xF))
// Swizzle for the 512x8 transpose tile: A = 8c + (hh ^ ((c>>1)&7)).
#define TSW(c, hh) (((c) << 3) + ((hh) ^ (((c) >> 1) & 7)))

// DPP helpers (VALU-only cross-lane within 16-lane rows; no LDS pipe).
#define DPP_SHR(x, n) __builtin_amdgcn_update_dpp(0, (x), 0x110 + (n), 0xF, 0xF, true)
#define DPP_SHL1(x)   __builtin_amdgcn_update_dpp(0, (x), 0x101,       0xF, 0xF, true)

__device__ __forceinline__ float2 cadd(float2 a, float2 b){ return make_float2(a.x+b.x, a.y+b.y); }
__device__ __forceinline__ float2 csub(float2 a, float2 b){ return make_float2(a.x-b.x, a.y-b.y); }
__device__ __forceinline__ float2 cmul(float2 a, float2 b){
    return make_float2(a.x*b.x - a.y*b.y, a.x*b.y + a.y*b.x);
}

// Nontemporal 8-byte store: drain fieldsT lines to memory DURING the row
// kernel instead of piling the writeback at its end (R8 theory test).
__device__ __forceinline__ void nt_store(float2* p, float2 v) {
    union { float2 f; double d; } u;
    u.f = v;
    __builtin_nontemporal_store(u.d, (double*)p);
}

// 8-point DFT, y_r = sum_u a_u * w8^{ru} (forward, w8 = exp(-i pi/4)).
__device__ __forceinline__ void dft8(const float2* a, float2* y) {
    const float s2 = 0.70710678118654752440f;
    float2 t02a = cadd(a[0], a[4]), t02s = csub(a[0], a[4]);
    float2 t13a = cadd(a[2], a[6]), t13s = csub(a[2], a[6]);
    float2 E0 = cadd(t02a, t13a);
    float2 E2 = csub(t02a, t13a);
    float2 E1 = make_float2(t02s.x + t13s.y, t02s.y - t13s.x);
    float2 E3 = make_float2(t02s.x - t13s.y, t02s.y + t13s.x);
    float2 u02a = cadd(a[1], a[5]), u02s = csub(a[1], a[5]);
    float2 u13a = cadd(a[3], a[7]), u13s = csub(a[3], a[7]);
    float2 O0 = cadd(u02a, u13a);
    float2 O2 = csub(u02a, u13a);
    float2 O1 = make_float2(u02s.x + u13s.y, u02s.y - u13s.x);
    float2 O3 = make_float2(u02s.x - u13s.y, u02s.y + u13s.x);
    float2 wO1 = make_float2(s2 * (O1.x + O1.y), s2 * (O1.y - O1.x));
    float2 wO2 = make_float2(O2.y, -O2.x);
    float2 wO3 = make_float2(s2 * (O3.y - O3.x), -s2 * (O3.x + O3.y));
    y[0] = cadd(E0, O0);  y[4] = csub(E0, O0);
    y[1] = cadd(E1, wO1); y[5] = csub(E1, wO1);
    y[2] = cadd(E2, wO2); y[6] = csub(E2, wO2);
    y[3] = cadd(E3, wO3); y[7] = csub(E3, wO3);
}

__device__ __forceinline__ void twiddle8(float base, float2* w) {
    float s1, c1, s4, c4;
    __sincosf(base, &s1, &c1);
    __sincosf(4.0f * base, &s4, &c4);
    w[0] = make_float2(1.0f, 0.0f);
    w[1] = make_float2(c1, s1);
    w[2] = cmul(w[1], w[1]);
    w[3] = cmul(w[2], w[1]);
    w[4] = make_float2(c4, s4);
    w[5] = cmul(w[4], w[1]);
    w[6] = cmul(w[4], w[2]);
    w[7] = cmul(w[4], w[3]);
}

// Radix-8 Stockham, N=512 (verified): 2 LDS round trips, wave-local.
__device__ __forceinline__ void fft512_stage0_store(float2* rb, int lane, const float2* a) {
    float2 y[8]; dft8(a, y);
    float2 w[8]; twiddle8(-PI_F * (float)lane * (1.0f / 256.0f), w);
#pragma unroll
    for (int r = 0; r < 8; ++r) rb[SW(8 * lane + r)] = cmul(y[r], w[r]);
}

__device__ __forceinline__ void fft512_stage1(float2* rb, int lane) {
    float2 a[8];
#pragma unroll
    for (int u = 0; u < 8; ++u) a[u] = rb[SW(lane + 64 * u)];
    float2 y[8]; dft8(a, y);
    float2 w[8]; twiddle8(-PI_F * (float)(lane >> 3) * (1.0f / 32.0f), w);
    const int qb = (lane & 7) + ((lane >> 3) << 6);
#pragma unroll
    for (int r = 0; r < 8; ++r) rb[SW(qb + 8 * r)] = cmul(y[r], w[r]);
}

__device__ __forceinline__ void fft512_stage2(const float2* rb, int lane, float2* y) {
    float2 a[8];
#pragma unroll
    for (int u = 0; u < 8; ++u) a[u] = rb[SW(lane + 64 * u)];
    dft8(a, y);   // twiddle-free; y[r] = X[lane + 64r] (natural order)
}

// ---------------------------------------------------------------------------
// Row pass (R8: transpose stores are NONTEMPORAL; layout = R7 pair-interleave:
// element (c,h) -> ((c>>1)<<10) + (h<<1) + (c&1), full 128B line per c-pair
// per block).
// ---------------------------------------------------------------------------
__global__ __launch_bounds__(512, 4)
void row_fft_kernel(const float2* __restrict__ z, const float2* __restrict__ t,
                    float2* __restrict__ fieldsT, int b0) {
    __shared__ float2 buf[8 * 512];   // 32 KiB: FFT regions, then transpose tile
    const int tid  = threadIdx.x;
    const int lane = tid & 63;
    const int g    = tid >> 6;
    const int bid  = blockIdx.x;
    const int hg   = bid & 63;
    const int lb   = bid >> 6;
    const int b    = b0 + lb;
    const int h    = (hg << 3) | g;
    const size_t rowOff = ((size_t)(b * HH + h)) * WW;

    const float2* tr = t + rowOff;
    const float2* zr = z + rowOff;
    float2 tv[8], zv[8];
#pragma unroll
    for (int u = 0; u < 8; ++u) tv[u] = tr[lane + 64 * u];
#pragma unroll
    for (int u = 0; u < 8; ++u) zv[u] = zr[lane + 64 * u];

    float2* rb = buf + (g << 9);
#pragma unroll
    for (int f = 0; f < 2; ++f) {
        float2 a[8];
        if (f == 0) {
#pragma unroll
            for (int u = 0; u < 8; ++u) a[u] = tv[u];
        } else {
#pragma unroll
            for (int u = 0; u < 8; ++u) a[u] = make_float2(zv[u].x - tv[u].x,
                                                           zv[u].y - tv[u].y);
        }
        fft512_stage0_store(rb, lane, a);
        __builtin_amdgcn_wave_barrier();
        fft512_stage1(rb, lane);
        __builtin_amdgcn_wave_barrier();
        float2 y[8];
        fft512_stage2(rb, lane, y);

        __syncthreads();   // all waves done reading their FFT regions
#pragma unroll
        for (int r = 0; r < 8; ++r) {
            int c = lane + (r << 6);
            buf[TSW(c, g)] = y[r];
        }
        __syncthreads();
        float2* outF = fieldsT + ((size_t)(lb * 2 + f) << 18);  // * 512*512
#pragma unroll
        for (int k = 0; k < 8; ++k) {
            int e  = tid + (k << 9);
            int c  = e >> 3;
            int hh = e & 7;
            int hr = (hg << 3) | hh;
            // pair-interleaved, nontemporal: drain during this kernel
            nt_store(&outF[((size_t)(c >> 1) << 10) + (hr << 1) + (c & 1)],
                     buf[TSW(c, hh)]);
        }
        __syncthreads();   // tile region free before next field's stage 0
    }
}

// ---------------------------------------------------------------------------
// Column pass: byte-identical to R7 (256 thr = 4 waves, one (column, field)
// per wave, 16 KiB LDS, pair-interleaved stride-2 reads, exact integer shell
// index + DPP segmented scan + wave-private LDS hist, non-atomic partials
// flush). grid = CH*2*128.
// ---------------------------------------------------------------------------
__global__ __launch_bounds__(256, 8)
void col_fft_bin_kernel(const float2* __restrict__ fieldsT,
                        float* __restrict__ partials, int b0) {
    __shared__ float2 buf[4 * 512];   // 16 KiB: 4 wave FFT regions (reused as hists)
    const int tid  = threadIdx.x;
    const int lane = tid & 63;
    const int g    = tid >> 6;        // 0..3
    const int bid  = blockIdx.x;
    const int cq   = bid & (NCQ - 1); // column quad
    const int f    = (bid >> 7) & 1;
    const int lb   = bid >> 8;
    const int b    = b0 + lb;
    const int c    = (cq << 2) | g;

    // element (c,h) at ((c>>1)<<10) + (h<<1) + (c&1)
    const float2* colT = fieldsT + ((size_t)(lb * 2 + f) << 18)
                                 + ((size_t)(c >> 1) << 10) + (c & 1);
    float2 a[8];
#pragma unroll
    for (int u = 0; u < 8; ++u) a[u] = colT[(lane + (u << 6)) << 1];

    float2* rb = buf + (g << 9);
    fft512_stage0_store(rb, lane, a);
    __builtin_amdgcn_wave_barrier();
    fft512_stage1(rb, lane);
    __builtin_amdgcn_wave_barrier();
    float2 y[8];
    fft512_stage2(rb, lane, y);
    __builtin_amdgcn_wave_barrier();
    __asm__ volatile("" ::: "memory");   // stage2 reads complete before hist zeroing

    // Zero the wave's private 512-float hist (first 256 float2 of its region).
#pragma unroll
    for (int j = 0; j < 4; ++j) rb[lane + (j << 6)] = make_float2(0.0f, 0.0f);
    __builtin_amdgcn_wave_barrier();
    __asm__ volatile("" ::: "memory");

    float* histw = (float*)rb;           // 512 wave-private bins
    const int dc = c - 256;
    const unsigned fc2i = (unsigned)(dc * dc);
    const int l15 = lane & 15;
#pragma unroll
    for (int r = 0; r < 8; ++r) {
        int k  = lane + (r << 6);
        int dk = k - 256;
        unsigned m = (unsigned)(dk * dk) + fc2i;   // 65536 * ellipse, exact
        // bin = #{ j in [1,511] : j^2 * 65536 <= 261121 * m }  (exact integer check)
        int bin = (int)(sqrtf((float)m) * (511.0f / 256.0f));
        unsigned long long rhs = 261121ull * (unsigned long long)m;  // 511^2 * m
        unsigned bp1 = (unsigned)(bin + 1);
        if (((unsigned long long)(bp1 * bp1) << 16) <= rhs) ++bin;
        else if (((unsigned long long)((unsigned)bin * (unsigned)bin) << 16) > rhs) --bin;
        bin = (m < 65536u) ? bin : 511;            // overflow shell -> bin 511 (dead)

        float v = y[r].x * y[r].x + y[r].y * y[r].y;

        // Segmented inclusive scan over equal-bin runs (bins monotone in lane),
        // VALU-only via DPP row_shr within each 16-lane row.
        int nb; float nv;
        nb = DPP_SHR(bin, 1);
        nv = __int_as_float(DPP_SHR(__float_as_int(v), 1));
        v += (l15 >= 1 && nb == bin) ? nv : 0.0f;
        nb = DPP_SHR(bin, 2);
        nv = __int_as_float(DPP_SHR(__float_as_int(v), 2));
        v += (l15 >= 2 && nb == bin) ? nv : 0.0f;
        nb = DPP_SHR(bin, 4);
        nv = __int_as_float(DPP_SHR(__float_as_int(v), 4));
        v += (l15 >= 4 && nb == bin) ? nv : 0.0f;
        nb = DPP_SHR(bin, 8);
        nv = __int_as_float(DPP_SHR(__float_as_int(v), 8));
        v += (l15 >= 8 && nb == bin) ? nv : 0.0f;

        int nxt = DPP_SHL1(bin);                   // bin of lane+1 within the row
        if (l15 == 15 || nxt != bin)               // last lane of its run
            atomicAdd(&histw[bin], v);
    }
    __syncthreads();                     // all 4 wave-private hists final

    // Cross-wave sum (4 regions, fixed order) + coalesced non-atomic flush.
    const float* bufF = (const float*)buf;
    float s0 = 0.0f, s1 = 0.0f;
#pragma unroll
    for (int w = 0; w < 4; ++w) {
        s0 += bufF[(w << 10) + tid];
        s1 += bufF[(w << 10) + 256 + tid];
    }
    const int fl = f * NBATCH + b;
    float* dst = partials + ((size_t)(cq << 5) + (size_t)fl) * NBINS;
    dst[tid] = s0;
    dst[tid + 256] = s1;
}

// ---------------------------------------------------------------------------
// Fold the 128 column-quad partials: bins[fl][bin] = sum_cq partials[cq][fl][bin].
// grid = 32 blocks (one per fl), block = 512.
// ---------------------------------------------------------------------------
__global__ __launch_bounds__(512)
void reduce_bins_kernel(const float* __restrict__ partials, float* __restrict__ bins) {
    const int tid = threadIdx.x;
    const int fl  = blockIdx.x;               // 0..31 (f*16+b)
    float s = 0.0f;
#pragma unroll 8
    for (int cq = 0; cq < NCQ; ++cq)
        s += partials[((size_t)(cq << 5) + fl) * NBINS + tid];
    bins[(size_t)fl * NBINS + tid] = s;
}

// ---------------------------------------------------------------------------
// Loss: single block reads the 64 KiB bins array.
// ---------------------------------------------------------------------------
__global__ __launch_bounds__(512)
void loss_kernel(const float* __restrict__ bins, float* __restrict__ outp) {
    __shared__ float red[512];
    const int tid = threadIdx.x;
    float acc = 0.0f;
    if (tid < 511) {
#pragma unroll 4
        for (int b = 0; b < NBATCH; ++b) {
            float ns = bins[((size_t)b) * NBINS + tid];
            float es = bins[((size_t)(NBATCH + b)) * NBINS + tid];
            acc += es / fmaxf(ns, 1e-8f);
        }
    }
    red[tid] = acc;
    __syncthreads();
    for (int s = 256; s > 0; s >>= 1) {
        if (tid < s) red[tid] += red[tid + s];
        __syncthreads();
    }
    if (tid == 0) outp[0] = red[0] * (1.0f / NBATCH);
}

// ---------------------------------------------------------------------------
// R8 launcher: software-pipelined double-buffered schedule. Two half-size
// intermediate buffers A/B; every col reads a buffer written >=1 full kernel
// earlier (drain distance), e.g. for CH=4:
//   rowA(0) rowB(4) colA(0) rowA(8) colB(4) rowB(12) colA(8) colB(12)
// Workspace: 8 MiB partials + 64 KiB bins + 2*CH*4 MiB buffers
// (CH=4 -> 40.06 MiB, known to fit since the old CB=8 layout did).
// ---------------------------------------------------------------------------
extern "C" void kernel_launch(void* const* d_in, const int* in_sizes, int n_in,
                              void* d_out, int out_size, void* d_ws, size_t ws_size,
                              hipStream_t stream) {
    const float2* z = (const float2*)d_in[0];
    const float2* t = (const float2*)d_in[1];
    float* outp = (float*)d_out;

    const size_t partialsBytes = (size_t)NCQ * 2 * NBATCH * NBINS * sizeof(float); // 8 MiB
    const size_t binsBytes     = (size_t)2 * NBATCH * NBINS * sizeof(float);       // 64 KiB
    const size_t fixedBytes    = partialsBytes + binsBytes;
    const size_t fpb = (size_t)2 * HH * WW * sizeof(float2);                       // 4 MiB/batch

    int CH = 4;
    while (CH > 1 && fixedBytes + (size_t)2 * CH * fpb > ws_size) CH >>= 1;

    float*  partials = (float*)d_ws;
    float*  bins     = (float*)((char*)d_ws + partialsBytes);
    float2* bufA     = (float2*)((char*)d_ws + fixedBytes);
    float2* bufB     = bufA + (size_t)CH * 2 * HH * WW;

    const int nch = NBATCH / CH;
    // No memset needed: every partials slot is written unconditionally
    // (all cq x all (f,b) covered across the chunks).
    for (int k = 0; k < nch; ++k) {
        float2* wbuf = (k & 1) ? bufB : bufA;
        row_fft_kernel<<<CH * 64, 512, 0, stream>>>(z, t, wbuf, k * CH);
        if (k >= 1) {
            float2* rbuf = ((k - 1) & 1) ? bufB : bufA;
            col_fft_bin_kernel<<<CH * 2 * NCQ, 256, 0, stream>>>(rbuf, partials,
                                                                 (k - 1) * CH);
        }
    }
    {
        float2* rbuf = ((nch - 1) & 1) ? bufB : bufA;
        col_fft_bin_kernel<<<CH * 2 * NCQ, 256, 0, stream>>>(rbuf, partials,
                                                             (nch - 1) * CH);
    }
    reduce_bins_kernel<<<32, 512, 0, stream>>>(partials, bins);
    loss_kernel<<<1, 512, 0, stream>>>(bins, outp);
}

// Round 9
// 174.554 us; speedup vs baseline: 1.0870x; 1.0870x over previous
//
#include <hip/hip_runtime.h>

#define HH 512
#define WW 512
#define NBATCH 16
#define NBINS 512   // 511 real shells + 1 overflow (never read downstream)
#define NCG 64      // column groups (8 columns per col-role block)

#define PI_F 3.14159265358979323846f

// Swizzle for the per-wave FFT exchange region (512 float2): keeps all three
// access phases at the conflict-free b64 baseline (verified, absmax 0).
#define SW(r) ((r) ^ (((r) >> 4) & 0xF))
// Swizzle for the 512x8 transpose tile: A = 8c + (hh ^ ((c>>1)&7)).
#define TSW(c, hh) (((c) << 3) + ((hh) ^ (((c) >> 1) & 7)))

// DPP helpers (VALU-only cross-lane within 16-lane rows; no LDS pipe).
#define DPP_SHR(x, n) __builtin_amdgcn_update_dpp(0, (x), 0x110 + (n), 0xF, 0xF, true)
#define DPP_SHL1(x)   __builtin_amdgcn_update_dpp(0, (x), 0x101,       0xF, 0xF, true)

__device__ __forceinline__ float2 cadd(float2 a, float2 b){ return make_float2(a.x+b.x, a.y+b.y); }
__device__ __forceinline__ float2 csub(float2 a, float2 b){ return make_float2(a.x-b.x, a.y-b.y); }
__device__ __forceinline__ float2 cmul(float2 a, float2 b){
    return make_float2(a.x*b.x - a.y*b.y, a.x*b.y + a.y*b.x);
}

// 8-point DFT, y_r = sum_u a_u * w8^{ru} (forward, w8 = exp(-i pi/4)).
__device__ __forceinline__ void dft8(const float2* a, float2* y) {
    const float s2 = 0.70710678118654752440f;
    float2 t02a = cadd(a[0], a[4]), t02s = csub(a[0], a[4]);
    float2 t13a = cadd(a[2], a[6]), t13s = csub(a[2], a[6]);
    float2 E0 = cadd(t02a, t13a);
    float2 E2 = csub(t02a, t13a);
    float2 E1 = make_float2(t02s.x + t13s.y, t02s.y - t13s.x);
    float2 E3 = make_float2(t02s.x - t13s.y, t02s.y + t13s.x);
    float2 u02a = cadd(a[1], a[5]), u02s = csub(a[1], a[5]);
    float2 u13a = cadd(a[3], a[7]), u13s = csub(a[3], a[7]);
    float2 O0 = cadd(u02a, u13a);
    float2 O2 = csub(u02a, u13a);
    float2 O1 = make_float2(u02s.x + u13s.y, u02s.y - u13s.x);
    float2 O3 = make_float2(u02s.x - u13s.y, u02s.y + u13s.x);
    float2 wO1 = make_float2(s2 * (O1.x + O1.y), s2 * (O1.y - O1.x));
    float2 wO2 = make_float2(O2.y, -O2.x);
    float2 wO3 = make_float2(s2 * (O3.y - O3.x), -s2 * (O3.x + O3.y));
    y[0] = cadd(E0, O0);  y[4] = csub(E0, O0);
    y[1] = cadd(E1, wO1); y[5] = csub(E1, wO1);
    y[2] = cadd(E2, wO2); y[6] = csub(E2, wO2);
    y[3] = cadd(E3, wO3); y[7] = csub(E3, wO3);
}

__device__ __forceinline__ void twiddle8(float base, float2* w) {
    float s1, c1, s4, c4;
    __sincosf(base, &s1, &c1);
    __sincosf(4.0f * base, &s4, &c4);
    w[0] = make_float2(1.0f, 0.0f);
    w[1] = make_float2(c1, s1);
    w[2] = cmul(w[1], w[1]);
    w[3] = cmul(w[2], w[1]);
    w[4] = make_float2(c4, s4);
    w[5] = cmul(w[4], w[1]);
    w[6] = cmul(w[4], w[2]);
    w[7] = cmul(w[4], w[3]);
}

// Radix-8 Stockham, N=512 (verified): 2 LDS round trips, wave-local.
__device__ __forceinline__ void fft512_stage0_store(float2* rb, int lane, const float2* a) {
    float2 y[8]; dft8(a, y);
    float2 w[8]; twiddle8(-PI_F * (float)lane * (1.0f / 256.0f), w);
#pragma unroll
    for (int r = 0; r < 8; ++r) rb[SW(8 * lane + r)] = cmul(y[r], w[r]);
}

__device__ __forceinline__ void fft512_stage1(float2* rb, int lane) {
    float2 a[8];
#pragma unroll
    for (int u = 0; u < 8; ++u) a[u] = rb[SW(lane + 64 * u)];
    float2 y[8]; dft8(a, y);
    float2 w[8]; twiddle8(-PI_F * (float)(lane >> 3) * (1.0f / 32.0f), w);
    const int qb = (lane & 7) + ((lane >> 3) << 6);
#pragma unroll
    for (int r = 0; r < 8; ++r) rb[SW(qb + 8 * r)] = cmul(y[r], w[r]);
}

__device__ __forceinline__ void fft512_stage2(const float2* rb, int lane, float2* y) {
    float2 a[8];
#pragma unroll
    for (int u = 0; u < 8; ++u) a[u] = rb[SW(lane + 64 * u)];
    dft8(a, y);   // twiddle-free; y[r] = X[lane + 64r] (natural order)
}

// ---------------------------------------------------------------------------
// Row role: identical to the proven R7 row kernel (plain stores, pair-
// interleaved layout: element (c,h) -> ((c>>1)<<10) + (h<<1) + (c&1); full
// 128B line per c-pair per block).
// ---------------------------------------------------------------------------
__device__ __forceinline__ void row_body(float2* buf,
                                         const float2* __restrict__ z,
                                         const float2* __restrict__ t,
                                         float2* __restrict__ fieldsT,
                                         int b0, int rbid) {
    const int tid  = threadIdx.x;
    const int lane = tid & 63;
    const int g    = tid >> 6;
    const int hg   = rbid & 63;
    const int lb   = rbid >> 6;
    const int b    = b0 + lb;
    const int h    = (hg << 3) | g;
    const size_t rowOff = ((size_t)(b * HH + h)) * WW;

    const float2* tr = t + rowOff;
    const float2* zr = z + rowOff;
    float2 tv[8], zv[8];
#pragma unroll
    for (int u = 0; u < 8; ++u) tv[u] = tr[lane + 64 * u];
#pragma unroll
    for (int u = 0; u < 8; ++u) zv[u] = zr[lane + 64 * u];

    float2* rb = buf + (g << 9);
#pragma unroll
    for (int f = 0; f < 2; ++f) {
        float2 a[8];
        if (f == 0) {
#pragma unroll
            for (int u = 0; u < 8; ++u) a[u] = tv[u];
        } else {
#pragma unroll
            for (int u = 0; u < 8; ++u) a[u] = make_float2(zv[u].x - tv[u].x,
                                                           zv[u].y - tv[u].y);
        }
        fft512_stage0_store(rb, lane, a);
        __builtin_amdgcn_wave_barrier();
        fft512_stage1(rb, lane);
        __builtin_amdgcn_wave_barrier();
        float2 y[8];
        fft512_stage2(rb, lane, y);

        __syncthreads();   // all waves done reading their FFT regions
#pragma unroll
        for (int r = 0; r < 8; ++r) {
            int c = lane + (r << 6);
            buf[TSW(c, g)] = y[r];
        }
        __syncthreads();
        float2* outF = fieldsT + ((size_t)(lb * 2 + f) << 18);  // * 512*512
#pragma unroll
        for (int k = 0; k < 8; ++k) {
            int e  = tid + (k << 9);
            int c  = e >> 3;
            int hh = e & 7;
            int hr = (hg << 3) | hh;
            outF[((size_t)(c >> 1) << 10) + (hr << 1) + (c & 1)] = buf[TSW(c, hh)];
        }
        __syncthreads();   // tile region free before next field's stage 0
    }
}

// ---------------------------------------------------------------------------
// Col role: R2's verified 8-wave body (wave g owns column (cg<<3)|g of one
// field) with R7's pair-interleaved stride-2 loads. Exact integer shell index
// + DPP segmented scan + wave-private LDS hist in the wave's own exchange
// region; one __syncthreads; non-atomic coalesced partials flush.
// ---------------------------------------------------------------------------
__device__ __forceinline__ void col_body(float2* buf,
                                         const float2* __restrict__ fieldsT,
                                         float* __restrict__ partials,
                                         int b0, int cbid) {
    const int tid  = threadIdx.x;
    const int lane = tid & 63;
    const int g    = tid >> 6;        // 0..7
    const int cg   = cbid & (NCG - 1);
    const int f    = (cbid >> 6) & 1;
    const int lb   = cbid >> 7;
    const int b    = b0 + lb;
    const int c    = (cg << 3) | g;

    // element (c,h) at ((c>>1)<<10) + (h<<1) + (c&1)
    const float2* colT = fieldsT + ((size_t)(lb * 2 + f) << 18)
                                 + ((size_t)(c >> 1) << 10) + (c & 1);
    float2 a[8];
#pragma unroll
    for (int u = 0; u < 8; ++u) a[u] = colT[(lane + (u << 6)) << 1];

    float2* rb = buf + (g << 9);
    fft512_stage0_store(rb, lane, a);
    __builtin_amdgcn_wave_barrier();
    fft512_stage1(rb, lane);
    __builtin_amdgcn_wave_barrier();
    float2 y[8];
    fft512_stage2(rb, lane, y);
    __builtin_amdgcn_wave_barrier();
    __asm__ volatile("" ::: "memory");   // stage2 reads complete before hist zeroing

    // Zero the wave's private 512-float hist (first 256 float2 of its region).
#pragma unroll
    for (int j = 0; j < 4; ++j) rb[lane + (j << 6)] = make_float2(0.0f, 0.0f);
    __builtin_amdgcn_wave_barrier();
    __asm__ volatile("" ::: "memory");

    float* histw = (float*)rb;           // 512 wave-private bins
    const int dc = c - 256;
    const unsigned fc2i = (unsigned)(dc * dc);
    const int l15 = lane & 15;
#pragma unroll
    for (int r = 0; r < 8; ++r) {
        int k  = lane + (r << 6);
        int dk = k - 256;
        unsigned m = (unsigned)(dk * dk) + fc2i;   // 65536 * ellipse, exact
        // bin = #{ j in [1,511] : j^2 * 65536 <= 261121 * m }  (exact integer check)
        int bin = (int)(sqrtf((float)m) * (511.0f / 256.0f));
        unsigned long long rhs = 261121ull * (unsigned long long)m;  // 511^2 * m
        unsigned bp1 = (unsigned)(bin + 1);
        if (((unsigned long long)(bp1 * bp1) << 16) <= rhs) ++bin;
        else if (((unsigned long long)((unsigned)bin * (unsigned)bin) << 16) > rhs) --bin;
        bin = (m < 65536u) ? bin : 511;            // overflow shell -> bin 511 (dead)

        float v = y[r].x * y[r].x + y[r].y * y[r].y;

        // Segmented inclusive scan over equal-bin runs (bins monotone in lane),
        // VALU-only via DPP row_shr within each 16-lane row.
        int nb; float nv;
        nb = DPP_SHR(bin, 1);
        nv = __int_as_float(DPP_SHR(__float_as_int(v), 1));
        v += (l15 >= 1 && nb == bin) ? nv : 0.0f;
        nb = DPP_SHR(bin, 2);
        nv = __int_as_float(DPP_SHR(__float_as_int(v), 2));
        v += (l15 >= 2 && nb == bin) ? nv : 0.0f;
        nb = DPP_SHR(bin, 4);
        nv = __int_as_float(DPP_SHR(__float_as_int(v), 4));
        v += (l15 >= 4 && nb == bin) ? nv : 0.0f;
        nb = DPP_SHR(bin, 8);
        nv = __int_as_float(DPP_SHR(__float_as_int(v), 8));
        v += (l15 >= 8 && nb == bin) ? nv : 0.0f;

        int nxt = DPP_SHL1(bin);                   // bin of lane+1 within the row
        if (l15 == 15 || nxt != bin)               // last lane of its run
            atomicAdd(&histw[bin], v);
    }
    __syncthreads();                     // all 8 wave-private hists final

    // Cross-wave sum (fixed order) + coalesced non-atomic flush.
    float s = 0.0f;
    const float* bufF = (const float*)buf;
#pragma unroll
    for (int gg = 0; gg < 8; ++gg) s += bufF[(gg << 10) + tid];
    const int fl = f * NBATCH + b;
    partials[(((size_t)cg << 5) + (size_t)fl) * NBINS + tid] = s;
}

// ---------------------------------------------------------------------------
// Fused kernel: row blocks for chunk k and col blocks for chunk k-1 run
// CONCURRENTLY in one launch (independent work; the only dependency --
// row(k-1) before col(k-1) -- is enforced by the previous launch's
// completion). Roles striped 1:2 mod 3 so both roles co-reside on every CU
// and col's latency stalls are filled by row's compute/stores.
// ---------------------------------------------------------------------------
__global__ __launch_bounds__(512, 4)
void fused_kernel(const float2* __restrict__ z, const float2* __restrict__ t,
                  float2* __restrict__ wbuf, const float2* __restrict__ rbuf,
                  float* __restrict__ partials,
                  int rowB0, int colB0, int nRow, int nCol) {
    __shared__ float2 buf[8 * 512];   // 32 KiB, shared by both roles
    const int bid = blockIdx.x;
    if (nRow > 0 && nCol > 0) {
        // nCol == 2*nRow: stripe [row, col, col] repeating
        const int q = bid / 3;
        const int r = bid - 3 * q;
        if (r == 0) row_body(buf, z, t, wbuf, rowB0, q);
        else        col_body(buf, rbuf, partials, colB0, 2 * q + (r - 1));
    } else if (nRow > 0) {
        row_body(buf, z, t, wbuf, rowB0, bid);
    } else {
        col_body(buf, rbuf, partials, colB0, bid);
    }
}

// ---------------------------------------------------------------------------
// Fold the 64 column-group partials: bins[fl][bin] = sum_cg partials[cg][fl][bin].
// grid = 128 blocks (verified R1/R2 shape).
// ---------------------------------------------------------------------------
__global__ __launch_bounds__(512)
void reduce_bins_kernel(const float* __restrict__ partials, float* __restrict__ bins) {
    __shared__ float red[512];
    const int tid = threadIdx.x;
    const int fl  = blockIdx.x >> 2;          // 0..31  (f*16+b)
    const int q   = blockIdx.x & 3;           // quarter of the 512 bins
    const int bin = (q << 7) + (tid & 127);
    const int ch  = tid >> 7;                 // 0..3 -> 16 cg each
    float s = 0.0f;
#pragma unroll
    for (int j = 0; j < 16; ++j) {
        int cg = (ch << 4) + j;
        s += partials[((size_t)(cg << 5) + fl) * NBINS + bin];
    }
    red[tid] = s;
    __syncthreads();
    if (tid < 128) {
        bins[(size_t)fl * NBINS + bin] =
            red[tid] + red[tid + 128] + red[tid + 256] + red[tid + 384];
    }
}

// ---------------------------------------------------------------------------
// Loss: single block reads the 64 KiB bins array.
// ---------------------------------------------------------------------------
__global__ __launch_bounds__(512)
void loss_kernel(const float* __restrict__ bins, float* __restrict__ outp) {
    __shared__ float red[512];
    const int tid = threadIdx.x;
    float acc = 0.0f;
    if (tid < 511) {
#pragma unroll 4
        for (int b = 0; b < NBATCH; ++b) {
            float ns = bins[((size_t)b) * NBINS + tid];
            float es = bins[((size_t)(NBATCH + b)) * NBINS + tid];
            acc += es / fmaxf(ns, 1e-8f);
        }
    }
    red[tid] = acc;
    __syncthreads();
    for (int s = 256; s > 0; s >>= 1) {
        if (tid < s) red[tid] += red[tid + s];
        __syncthreads();
    }
    if (tid == 0) outp[0] = red[0] * (1.0f / NBATCH);
}

// ---------------------------------------------------------------------------
// R9 launcher: software-pipelined fused schedule, CH=4 (double-buffered):
//   L0: row(0)            -> A
//   L1: row(1)->B || col(0)<-A
//   L2: row(2)->A || col(1)<-B
//   L3: row(3)->B || col(2)<-A
//   L4:            col(3)<-B
// Workspace: 4 MiB partials + 64 KiB bins + 2*CH*4 MiB buffers (36 MiB @CH=4).
// ---------------------------------------------------------------------------
extern "C" void kernel_launch(void* const* d_in, const int* in_sizes, int n_in,
                              void* d_out, int out_size, void* d_ws, size_t ws_size,
                              hipStream_t stream) {
    const float2* z = (const float2*)d_in[0];
    const float2* t = (const float2*)d_in[1];
    float* outp = (float*)d_out;

    const size_t partialsBytes = (size_t)NCG * 2 * NBATCH * NBINS * sizeof(float); // 4 MiB
    const size_t binsBytes     = (size_t)2 * NBATCH * NBINS * sizeof(float);       // 64 KiB
    const size_t fixedBytes    = partialsBytes + binsBytes;
    const size_t fpb = (size_t)2 * HH * WW * sizeof(float2);                       // 4 MiB/batch

    int CH = 4;
    while (CH > 1 && fixedBytes + (size_t)2 * CH * fpb > ws_size) CH >>= 1;

    float*  partials = (float*)d_ws;
    float*  bins     = (float*)((char*)d_ws + partialsBytes);
    float2* bufA     = (float2*)((char*)d_ws + fixedBytes);
    float2* bufB     = bufA + (size_t)CH * 2 * HH * WW;

    const int nch = NBATCH / CH;
    // No memset needed: every partials slot is written unconditionally
    // (all cg x all (f,b) covered across the chunks).
    for (int k = 0; k <= nch; ++k) {
        const int nRow = (k < nch) ? CH * 64 : 0;
        const int nCol = (k > 0) ? CH * 2 * NCG : 0;
        float2* wbuf = (k & 1) ? bufB : bufA;
        const float2* rbuf = (k > 0) ? (((k - 1) & 1) ? bufB : bufA) : bufA;
        fused_kernel<<<nRow + nCol, 512, 0, stream>>>(z, t, wbuf, rbuf, partials,
                                                      k * CH, (k - 1) * CH,
                                                      nRow, nCol);
    }
    reduce_bins_kernel<<<128, 512, 0, stream>>>(partials, bins);
    loss_kernel<<<1, 512, 0, stream>>>(bins, outp);
}

// Round 10
// 160.242 us; speedup vs baseline: 1.1841x; 1.0893x over previous
//
#include <hip/hip_runtime.h>
#include <hip/hip_fp16.h>

#define HH 512
#define WW 512
#define NBATCH 16
#define NBINS 512   // 511 real shells + 1 overflow (never read downstream)
#define NCG 64      // column groups (8 columns per col block)

#define PI_F 3.14159265358979323846f

// Swizzle for the per-wave FFT exchange region (512 float2): keeps all three
// access phases at the conflict-free b64 baseline (verified, absmax 0).
#define SW(r) ((r) ^ (((r) >> 4) & 0xF))
// Swizzle for the 512x8 transpose tile: A = 8c + (hh ^ ((c>>1)&7)).
#define TSW(c, hh) (((c) << 3) + ((hh) ^ (((c) >> 1) & 7)))

// DPP helpers (VALU-only cross-lane within 16-lane rows; no LDS pipe).
#define DPP_SHR(x, n) __builtin_amdgcn_update_dpp(0, (x), 0x110 + (n), 0xF, 0xF, true)
#define DPP_SHL1(x)   __builtin_amdgcn_update_dpp(0, (x), 0x101,       0xF, 0xF, true)

__device__ __forceinline__ float2 cadd(float2 a, float2 b){ return make_float2(a.x+b.x, a.y+b.y); }
__device__ __forceinline__ float2 csub(float2 a, float2 b){ return make_float2(a.x-b.x, a.y-b.y); }
__device__ __forceinline__ float2 cmul(float2 a, float2 b){
    return make_float2(a.x*b.x - a.y*b.y, a.x*b.y + a.y*b.x);
}

// fp16 pack/unpack for the intermediate (stored as u32 = __half2 bits).
__device__ __forceinline__ unsigned f2h(float2 v) {
    union { unsigned u; __half2 h; } cv;
    cv.h = __float22half2_rn(v);
    return cv.u;
}
__device__ __forceinline__ float2 h2f(unsigned u) {
    union { unsigned u; __half2 h; } cv;
    cv.u = u;
    return __half22float2(cv.h);
}

// 8-point DFT, y_r = sum_u a_u * w8^{ru} (forward, w8 = exp(-i pi/4)).
__device__ __forceinline__ void dft8(const float2* a, float2* y) {
    const float s2 = 0.70710678118654752440f;
    float2 t02a = cadd(a[0], a[4]), t02s = csub(a[0], a[4]);
    float2 t13a = cadd(a[2], a[6]), t13s = csub(a[2], a[6]);
    float2 E0 = cadd(t02a, t13a);
    float2 E2 = csub(t02a, t13a);
    float2 E1 = make_float2(t02s.x + t13s.y, t02s.y - t13s.x);
    float2 E3 = make_float2(t02s.x - t13s.y, t02s.y + t13s.x);
    float2 u02a = cadd(a[1], a[5]), u02s = csub(a[1], a[5]);
    float2 u13a = cadd(a[3], a[7]), u13s = csub(a[3], a[7]);
    float2 O0 = cadd(u02a, u13a);
    float2 O2 = csub(u02a, u13a);
    float2 O1 = make_float2(u02s.x + u13s.y, u02s.y - u13s.x);
    float2 O3 = make_float2(u02s.x - u13s.y, u02s.y + u13s.x);
    float2 wO1 = make_float2(s2 * (O1.x + O1.y), s2 * (O1.y - O1.x));
    float2 wO2 = make_float2(O2.y, -O2.x);
    float2 wO3 = make_float2(s2 * (O3.y - O3.x), -s2 * (O3.x + O3.y));
    y[0] = cadd(E0, O0);  y[4] = csub(E0, O0);
    y[1] = cadd(E1, wO1); y[5] = csub(E1, wO1);
    y[2] = cadd(E2, wO2); y[6] = csub(E2, wO2);
    y[3] = cadd(E3, wO3); y[7] = csub(E3, wO3);
}

__device__ __forceinline__ void twiddle8(float base, float2* w) {
    float s1, c1, s4, c4;
    __sincosf(base, &s1, &c1);
    __sincosf(4.0f * base, &s4, &c4);
    w[0] = make_float2(1.0f, 0.0f);
    w[1] = make_float2(c1, s1);
    w[2] = cmul(w[1], w[1]);
    w[3] = cmul(w[2], w[1]);
    w[4] = make_float2(c4, s4);
    w[5] = cmul(w[4], w[1]);
    w[6] = cmul(w[4], w[2]);
    w[7] = cmul(w[4], w[3]);
}

// Radix-8 Stockham, N=512 (verified): 2 LDS round trips, wave-local.
__device__ __forceinline__ void fft512_stage0_store(float2* rb, int lane, const float2* a) {
    float2 y[8]; dft8(a, y);
    float2 w[8]; twiddle8(-PI_F * (float)lane * (1.0f / 256.0f), w);
#pragma unroll
    for (int r = 0; r < 8; ++r) rb[SW(8 * lane + r)] = cmul(y[r], w[r]);
}

__device__ __forceinline__ void fft512_stage1(float2* rb, int lane) {
    float2 a[8];
#pragma unroll
    for (int u = 0; u < 8; ++u) a[u] = rb[SW(lane + 64 * u)];
    float2 y[8]; dft8(a, y);
    float2 w[8]; twiddle8(-PI_F * (float)(lane >> 3) * (1.0f / 32.0f), w);
    const int qb = (lane & 7) + ((lane >> 3) << 6);
#pragma unroll
    for (int r = 0; r < 8; ++r) rb[SW(qb + 8 * r)] = cmul(y[r], w[r]);
}

__device__ __forceinline__ void fft512_stage2(const float2* rb, int lane, float2* y) {
    float2 a[8];
#pragma unroll
    for (int u = 0; u < 8; ++u) a[u] = rb[SW(lane + 64 * u)];
    dft8(a, y);   // twiddle-free; y[r] = X[lane + 64r] (natural order)
}

// ---------------------------------------------------------------------------
// Row pass (R10): fp32 FFT, then the transpose store converts to fp16 and
// writes the sigma-permuted column layout:
//   element (c, h) -> fieldsH[fl][c][sigma(h)],  sigma(h) = 8*(h&63) + (h>>6)
// so a col wave's 8 FFT inputs X[lane + 64u] are 8 CONSECUTIVE half2 =
// two uint4 (b128) loads. Stores become scattered 4 B — on the proven-free
// write path (R5: +20 MB of atomic writes cost nothing).
// ---------------------------------------------------------------------------
__global__ __launch_bounds__(512, 4)
void row_fft_kernel(const float2* __restrict__ z, const float2* __restrict__ t,
                    unsigned* __restrict__ fieldsH, int b0) {
    __shared__ float2 buf[8 * 512];   // 32 KiB: FFT regions, then transpose tile
    const int tid  = threadIdx.x;
    const int lane = tid & 63;
    const int g    = tid >> 6;
    const int bid  = blockIdx.x;
    const int hg   = bid & 63;
    const int lb   = bid >> 6;
    const int b    = b0 + lb;
    const int h    = (hg << 3) | g;
    const size_t rowOff = ((size_t)(b * HH + h)) * WW;

    const float2* tr = t + rowOff;
    const float2* zr = z + rowOff;
    float2 tv[8], zv[8];
#pragma unroll
    for (int u = 0; u < 8; ++u) tv[u] = tr[lane + 64 * u];
#pragma unroll
    for (int u = 0; u < 8; ++u) zv[u] = zr[lane + 64 * u];

    float2* rb = buf + (g << 9);
#pragma unroll
    for (int f = 0; f < 2; ++f) {
        float2 a[8];
        if (f == 0) {
#pragma unroll
            for (int u = 0; u < 8; ++u) a[u] = tv[u];
        } else {
#pragma unroll
            for (int u = 0; u < 8; ++u) a[u] = make_float2(zv[u].x - tv[u].x,
                                                           zv[u].y - tv[u].y);
        }
        fft512_stage0_store(rb, lane, a);
        __builtin_amdgcn_wave_barrier();
        fft512_stage1(rb, lane);
        __builtin_amdgcn_wave_barrier();
        float2 y[8];
        fft512_stage2(rb, lane, y);

        __syncthreads();   // all waves done reading their FFT regions
#pragma unroll
        for (int r = 0; r < 8; ++r) {
            int c = lane + (r << 6);
            buf[TSW(c, g)] = y[r];
        }
        __syncthreads();
        unsigned* outF = fieldsH + ((size_t)(lb * 2 + f) << 18);  // * 512*512
#pragma unroll
        for (int k = 0; k < 8; ++k) {
            int e  = tid + (k << 9);
            int c  = e >> 3;
            int hh = e & 7;
            int hr = (hg << 3) | hh;
            // sigma(hr) = 8*(hr&63) + (hr>>6)
            outF[((size_t)c << 9) + (((hr & 63) << 3) | (hr >> 6))] =
                f2h(buf[TSW(c, hh)]);
        }
        __syncthreads();   // tile region free before next field's stage 0
    }
}

// ---------------------------------------------------------------------------
// Column pass (R10): R2's verified 8-wave body, but the column load is TWO
// uint4 (b128) loads per lane from the sigma-permuted fp16 layout — element
// p = 8*lane + j holds X[64*j + lane], i.e. a[j]. Bytes halved AND load
// instruction count quartered vs R0-R9. Everything downstream (fp32 FFT,
// exact integer shell index, DPP segmented scan, wave-private LDS hist,
// non-atomic partials flush) is the verified body, unchanged.
// grid = CB*2*64.
// ---------------------------------------------------------------------------
__global__ __launch_bounds__(512, 4)
void col_fft_bin_kernel(const unsigned* __restrict__ fieldsH,
                        float* __restrict__ partials, int b0) {
    __shared__ float2 buf[8 * 512];   // 32 KiB FFT exchange regions (reused as hists)
    const int tid  = threadIdx.x;
    const int lane = tid & 63;
    const int g    = tid >> 6;        // 0..7
    const int bid  = blockIdx.x;
    const int cg   = bid & (NCG - 1);
    const int f    = (bid >> 6) & 1;
    const int lb   = bid >> 7;
    const int b    = b0 + lb;
    const int c    = (cg << 3) | g;

    const uint4* colQ = reinterpret_cast<const uint4*>(
        fieldsH + ((size_t)(lb * 2 + f) << 18) + ((size_t)c << 9));
    uint4 q0 = colQ[2 * lane];
    uint4 q1 = colQ[2 * lane + 1];
    float2 a[8];
    a[0] = h2f(q0.x); a[1] = h2f(q0.y); a[2] = h2f(q0.z); a[3] = h2f(q0.w);
    a[4] = h2f(q1.x); a[5] = h2f(q1.y); a[6] = h2f(q1.z); a[7] = h2f(q1.w);

    float2* rb = buf + (g << 9);
    fft512_stage0_store(rb, lane, a);
    __builtin_amdgcn_wave_barrier();
    fft512_stage1(rb, lane);
    __builtin_amdgcn_wave_barrier();
    float2 y[8];
    fft512_stage2(rb, lane, y);
    __builtin_amdgcn_wave_barrier();
    __asm__ volatile("" ::: "memory");   // stage2 reads complete before hist zeroing

    // Zero the wave's private 512-float hist (first 256 float2 of its region).
#pragma unroll
    for (int j = 0; j < 4; ++j) rb[lane + (j << 6)] = make_float2(0.0f, 0.0f);
    __builtin_amdgcn_wave_barrier();
    __asm__ volatile("" ::: "memory");

    float* histw = (float*)rb;           // 512 wave-private bins
    const int dc = c - 256;
    const unsigned fc2i = (unsigned)(dc * dc);
    const int l15 = lane & 15;
#pragma unroll
    for (int r = 0; r < 8; ++r) {
        int k  = lane + (r << 6);
        int dk = k - 256;
        unsigned m = (unsigned)(dk * dk) + fc2i;   // 65536 * ellipse, exact
        // bin = #{ j in [1,511] : j^2 * 65536 <= 261121 * m }  (exact integer check)
        int bin = (int)(sqrtf((float)m) * (511.0f / 256.0f));
        unsigned long long rhs = 261121ull * (unsigned long long)m;  // 511^2 * m
        unsigned bp1 = (unsigned)(bin + 1);
        if (((unsigned long long)(bp1 * bp1) << 16) <= rhs) ++bin;
        else if (((unsigned long long)((unsigned)bin * (unsigned)bin) << 16) > rhs) --bin;
        bin = (m < 65536u) ? bin : 511;            // overflow shell -> bin 511 (dead)

        float v = y[r].x * y[r].x + y[r].y * y[r].y;

        // Segmented inclusive scan over equal-bin runs (bins monotone in lane),
        // VALU-only via DPP row_shr within each 16-lane row.
        int nb; float nv;
        nb = DPP_SHR(bin, 1);
        nv = __int_as_float(DPP_SHR(__float_as_int(v), 1));
        v += (l15 >= 1 && nb == bin) ? nv : 0.0f;
        nb = DPP_SHR(bin, 2);
        nv = __int_as_float(DPP_SHR(__float_as_int(v), 2));
        v += (l15 >= 2 && nb == bin) ? nv : 0.0f;
        nb = DPP_SHR(bin, 4);
        nv = __int_as_float(DPP_SHR(__float_as_int(v), 4));
        v += (l15 >= 4 && nb == bin) ? nv : 0.0f;
        nb = DPP_SHR(bin, 8);
        nv = __int_as_float(DPP_SHR(__float_as_int(v), 8));
        v += (l15 >= 8 && nb == bin) ? nv : 0.0f;

        int nxt = DPP_SHL1(bin);                   // bin of lane+1 within the row
        if (l15 == 15 || nxt != bin)               // last lane of its run
            atomicAdd(&histw[bin], v);
    }
    __syncthreads();                     // all 8 wave-private hists final

    // Cross-wave sum (fixed order) + coalesced non-atomic flush.
    float s = 0.0f;
    const float* bufF = (const float*)buf;
#pragma unroll
    for (int gg = 0; gg < 8; ++gg) s += bufF[(gg << 10) + tid];
    const int fl = f * NBATCH + b;
    partials[(((size_t)cg << 5) + (size_t)fl) * NBINS + tid] = s;
}

// ---------------------------------------------------------------------------
// Fold the 64 column-group partials: bins[fl][bin] = sum_cg partials[cg][fl][bin].
// grid = 128 blocks (verified shape).
// ---------------------------------------------------------------------------
__global__ __launch_bounds__(512)
void reduce_bins_kernel(const float* __restrict__ partials, float* __restrict__ bins) {
    __shared__ float red[512];
    const int tid = threadIdx.x;
    const int fl  = blockIdx.x >> 2;          // 0..31  (f*16+b)
    const int q   = blockIdx.x & 3;           // quarter of the 512 bins
    const int bin = (q << 7) + (tid & 127);
    const int ch  = tid >> 7;                 // 0..3 -> 16 cg each
    float s = 0.0f;
#pragma unroll
    for (int j = 0; j < 16; ++j) {
        int cg = (ch << 4) + j;
        s += partials[((size_t)(cg << 5) + fl) * NBINS + bin];
    }
    red[tid] = s;
    __syncthreads();
    if (tid < 128) {
        bins[(size_t)fl * NBINS + bin] =
            red[tid] + red[tid + 128] + red[tid + 256] + red[tid + 384];
    }
}

// ---------------------------------------------------------------------------
// Loss: single block reads the 64 KiB bins array.
// ---------------------------------------------------------------------------
__global__ __launch_bounds__(512)
void loss_kernel(const float* __restrict__ bins, float* __restrict__ outp) {
    __shared__ float red[512];
    const int tid = threadIdx.x;
    float acc = 0.0f;
    if (tid < 511) {
#pragma unroll 4
        for (int b = 0; b < NBATCH; ++b) {
            float ns = bins[((size_t)b) * NBINS + tid];
            float es = bins[((size_t)(NBATCH + b)) * NBINS + tid];
            acc += es / fmaxf(ns, 1e-8f);
        }
    }
    red[tid] = acc;
    __syncthreads();
    for (int s = 256; s > 0; s >>= 1) {
        if (tid < s) red[tid] += red[tid + s];
        __syncthreads();
    }
    if (tid == 0) outp[0] = red[0] * (1.0f / NBATCH);
}

// ---------------------------------------------------------------------------
// R10 launcher: fp16 intermediate -> whole problem in ONE pass (CB=16):
// workspace = 4 MiB partials + 64 KiB bins + 32 MiB fieldsH = 36.1 MiB.
// Chunk fallback retained in case ws_size is smaller.
// ---------------------------------------------------------------------------
extern "C" void kernel_launch(void* const* d_in, const int* in_sizes, int n_in,
                              void* d_out, int out_size, void* d_ws, size_t ws_size,
                              hipStream_t stream) {
    const float2* z = (const float2*)d_in[0];
    const float2* t = (const float2*)d_in[1];
    float* outp = (float*)d_out;

    const size_t partialsBytes = (size_t)NCG * 2 * NBATCH * NBINS * sizeof(float); // 4 MiB
    const size_t binsBytes     = (size_t)2 * NBATCH * NBINS * sizeof(float);       // 64 KiB
    const size_t fixedBytes    = partialsBytes + binsBytes;
    const size_t fpb = (size_t)2 * HH * WW * sizeof(unsigned);                     // 2 MiB/batch

    int CB = 16;
    while (CB > 1 && fixedBytes + (size_t)CB * fpb > ws_size) CB >>= 1;

    float*    partials = (float*)d_ws;
    float*    bins     = (float*)((char*)d_ws + partialsBytes);
    unsigned* fieldsH  = (unsigned*)((char*)d_ws + fixedBytes);

    // No memset needed: every partials slot is written unconditionally
    // (all cg x all (f,b) covered across the chunks).
    for (int b0 = 0; b0 < NBATCH; b0 += CB) {
        row_fft_kernel<<<CB * 64, 512, 0, stream>>>(z, t, fieldsH, b0);
        col_fft_bin_kernel<<<CB * 2 * NCG, 512, 0, stream>>>(fieldsH, partials, b0);
    }
    reduce_bins_kernel<<<128, 512, 0, stream>>>(partials, bins);
    loss_kernel<<<1, 512, 0, stream>>>(bins, outp);
}